// Round 1
// baseline (656.219 us; speedup 1.0000x reference)
//
#include <hip/hip_runtime.h>

#define DIM 128

// ---- order-preserving float<->uint encoding for atomicMax on floats ----
__device__ __forceinline__ unsigned encf(float f) {
    unsigned u = __float_as_uint(f);
    return (u & 0x80000000u) ? ~u : (u | 0x80000000u);
}
__device__ __forceinline__ float decf(unsigned e) {
    return __uint_as_float((e & 0x80000000u) ? (e & 0x7FFFFFFFu) : ~e);
}

// enc(-inf): bits(-inf)=0xFF800000 (negative) -> ~0xFF800000 = 0x007FFFFF
#define ENC_NEG_INF 0x007FFFFFu

// ---- init per-node max/sum arrays ----
__global__ void k_init(unsigned* __restrict__ umax, float* __restrict__ usum, int nu,
                       unsigned* __restrict__ imax, float* __restrict__ isum, int ni) {
    int t = blockIdx.x * blockDim.x + threadIdx.x;
    int stride = gridDim.x * blockDim.x;
    for (int j = t; j < nu; j += stride) { umax[j] = ENC_NEG_INF; usum[j] = 0.f; }
    for (int j = t; j < ni; j += stride) { imax[j] = ENC_NEG_INF; isum[j] = 0.f; }
}

// ---- per-node dot with attention weight vector (one wave per row) ----
__global__ void k_dots(const float* __restrict__ emb, const float* __restrict__ w,
                       float* __restrict__ out, int nrows) {
    int gwid = (blockIdx.x * blockDim.x + threadIdx.x) >> 6;  // global wave id
    int lane = threadIdx.x & 63;
    if (gwid >= nrows) return;
    const float2* row = (const float2*)(emb + (size_t)gwid * DIM);
    const float2* wv  = (const float2*)w;
    float2 a = row[lane];
    float2 b = wv[lane];
    float v = a.x * b.x + a.y * b.y;
    #pragma unroll
    for (int off = 32; off; off >>= 1) v += __shfl_down(v, off);
    if (lane == 0) out[gwid] = v;
}

// ---- per-edge raw score + leaky relu + segment max (both groupings) ----
__global__ void k_raw(const int* __restrict__ uidx, const int* __restrict__ iidx,
                      const float* __restrict__ su, const float* __restrict__ si,
                      float* __restrict__ raw, unsigned* __restrict__ umax,
                      unsigned* __restrict__ imax, int ne) {
    int e = blockIdx.x * blockDim.x + threadIdx.x;
    if (e >= ne) return;
    int u = uidx[e], i = iidx[e];
    float r = su[u] + si[i];
    r = (r >= 0.f) ? r : 0.2f * r;
    raw[e] = r;
    unsigned enc = encf(r);
    atomicMax(&umax[u], enc);
    atomicMax(&imax[i], enc);
}

// ---- per-edge exp + segment sums ----
__global__ void k_exp(const int* __restrict__ uidx, const int* __restrict__ iidx,
                      const float* __restrict__ raw,
                      const unsigned* __restrict__ umax, const unsigned* __restrict__ imax,
                      float* __restrict__ eu, float* __restrict__ ei,
                      float* __restrict__ usum, float* __restrict__ isum, int ne) {
    int e = blockIdx.x * blockDim.x + threadIdx.x;
    if (e >= ne) return;
    int u = uidx[e], i = iidx[e];
    float r = raw[e];
    float x = expf(r - decf(umax[u]));
    float y = expf(r - decf(imax[i]));
    eu[e] = x; ei[e] = y;
    atomicAdd(&usum[u], x);
    atomicAdd(&isum[i], y);
}

// ---- copy embeddings into outputs (float4, grid-stride) ----
__global__ void k_copy(const float4* __restrict__ src, float4* __restrict__ dst, size_t n4) {
    size_t t = (size_t)blockIdx.x * blockDim.x + threadIdx.x;
    size_t stride = (size_t)gridDim.x * blockDim.x;
    for (size_t j = t; j < n4; j += stride) dst[j] = src[j];
}

// ---- per-edge scatter-add of attn-weighted rows (2 edges per 256-thread block) ----
__global__ void k_scatter(const int* __restrict__ uidx, const int* __restrict__ iidx,
                          const float* __restrict__ u_emb, const float* __restrict__ i_emb,
                          const float* __restrict__ eu, const float* __restrict__ ei,
                          const float* __restrict__ usum, const float* __restrict__ isum,
                          float* __restrict__ out_u, float* __restrict__ out_i, int ne) {
    int e = blockIdx.x * (blockDim.x / DIM) + (threadIdx.x / DIM);
    int d = threadIdx.x & (DIM - 1);
    if (e >= ne) return;
    int u = uidx[e], i = iidx[e];
    float au = eu[e] / (usum[u] + 1e-10f);
    float ai = ei[e] / (isum[i] + 1e-10f);
    atomicAdd(&out_u[(size_t)u * DIM + d], i_emb[(size_t)i * DIM + d] * au);
    atomicAdd(&out_i[(size_t)i * DIM + d], u_emb[(size_t)u * DIM + d] * ai);
}

extern "C" void kernel_launch(void* const* d_in, const int* in_sizes, int n_in,
                              void* d_out, int out_size, void* d_ws, size_t ws_size,
                              hipStream_t stream) {
    const float* u_emb  = (const float*)d_in[0];
    const float* i_emb  = (const float*)d_in[1];
    const int*   edge   = (const int*)d_in[2];
    // d_in[3] = weights, unused by the reference
    const float* attn_w = (const float*)d_in[4];

    const int nu = in_sizes[0] / DIM;
    const int ni = in_sizes[1] / DIM;
    const int ne = in_sizes[3];

    const int* uidx = edge;
    const int* iidx = edge + ne;

    float* out_u = (float*)d_out;
    float* out_i = out_u + (size_t)nu * DIM;

    // workspace carve-up (16B aligned chunks)
    char* ws = (char*)d_ws;
    auto take = [&](size_t bytes) { char* p = ws; ws += (bytes + 15) & ~size_t(15); return p; };
    float*    su   = (float*)   take(nu * sizeof(float));
    float*    si   = (float*)   take(ni * sizeof(float));
    unsigned* umax = (unsigned*)take(nu * sizeof(unsigned));
    unsigned* imax = (unsigned*)take(ni * sizeof(unsigned));
    float*    usum = (float*)   take(nu * sizeof(float));
    float*    isum = (float*)   take(ni * sizeof(float));
    float*    raw  = (float*)   take(ne * sizeof(float));
    float*    eu   = (float*)   take(ne * sizeof(float));
    float*    ei   = (float*)   take(ne * sizeof(float));

    // 1. init max/sum arrays
    k_init<<<256, 256, 0, stream>>>(umax, usum, nu, imax, isum, ni);

    // 2. per-node dots (one wave per row, 4 waves/block)
    k_dots<<<(nu + 3) / 4, 256, 0, stream>>>(u_emb, attn_w,       su, nu);
    k_dots<<<(ni + 3) / 4, 256, 0, stream>>>(i_emb, attn_w + DIM, si, ni);

    // 3. raw scores + segment max
    k_raw<<<(ne + 255) / 256, 256, 0, stream>>>(uidx, iidx, su, si, raw, umax, imax, ne);

    // 4. exp + segment sums
    k_exp<<<(ne + 255) / 256, 256, 0, stream>>>(uidx, iidx, raw, umax, imax, eu, ei, usum, isum, ne);

    // 5. out = emb (copy both tables; contiguous in d_out)
    {
        size_t n4 = (size_t)out_size / 4;  // out_size = (nu+ni)*DIM, DIM%4==0
        k_copy<<<2048, 256, 0, stream>>>((const float4*)u_emb, (float4*)out_u, (size_t)nu * DIM / 4);
        k_copy<<<1024, 256, 0, stream>>>((const float4*)i_emb, (float4*)out_i, (size_t)ni * DIM / 4);
        (void)n4;
    }

    // 6. scatter-add attn-weighted neighbor rows
    k_scatter<<<(ne + 1) / 2, 256, 0, stream>>>(uidx, iidx, u_emb, i_emb, eu, ei,
                                                usum, isum, out_u, out_i, ne);
}